// Round 14
// baseline (487.097 us; speedup 1.0000x reference)
//
#include <hip/hip_runtime.h>
#include <stdint.h>

typedef unsigned short u16;
typedef __attribute__((ext_vector_type(8))) short short8;
typedef __attribute__((ext_vector_type(4))) float f32x4;
typedef __attribute__((ext_vector_type(16))) float f32x16;

#define NCTX 4096
#define NTGT 2048
#define DMODEL 1024
#define NH 16
#define HD 64

typedef const __attribute__((address_space(1))) uint32_t g_u32;
typedef __attribute__((address_space(3))) uint32_t lds_u32;

__device__ inline u16 f2b(float f) {
  unsigned r;
  asm("v_cvt_pk_bf16_f32 %0, %1, %1" : "=v"(r) : "v"(f));
  return (u16)r;
}
__device__ inline uint32_t pk2(float lo, float hi_) {
  uint32_t r;
  asm("v_cvt_pk_bf16_f32 %0, %1, %2" : "=v"(r) : "v"(lo), "v"(hi_));
  return r;
}

// ---------------- f32 -> bf16 conversion ----------------
__global__ void cvt_bf16(const float* __restrict__ in, u16* __restrict__ out, int n4) {
  int i = blockIdx.x * blockDim.x + threadIdx.x;
  if (i >= n4) return;
  const float4 v = ((const float4*)in)[i];
  ((uint2*)out)[i] = make_uint2(pk2(v.x, v.y), pk2(v.z, v.w));
}

// ---------------- generic C = A * B^T  (bf16 in, f32 accum) ----------------
// MODE 1: K-writer; Ck is pre-scaled by beta*log2e (used only for scores).
template<int MODE>
__global__ __launch_bounds__(256) void gemm_bt(
    const u16* __restrict__ A, const u16* __restrict__ B,
    float* __restrict__ Cf, u16* __restrict__ Ck, u16* __restrict__ Ckt,
    int M, int N, int Kd) {
  const int bm = blockIdx.x % (M >> 6);
  const int bn = blockIdx.x / (M >> 6);
  const int w = threadIdx.x >> 6, l = threadIdx.x & 63;
  const int lg = l >> 4, lm = l & 15;
  const int m0 = (bm << 6) + (w << 4);
  const int n0 = bn << 6;

  const u16* Ar = A + (size_t)(m0 + lm) * Kd;
  f32x4 acc[4] = {};

  for (int kd = 0; kd < Kd; kd += 64) {
    short8 a0 = *(const short8*)(Ar + kd + lg * 8);
    short8 a1 = *(const short8*)(Ar + kd + 32 + lg * 8);
#pragma unroll
    for (int nf = 0; nf < 4; ++nf) {
      const u16* Br = B + (size_t)(n0 + nf * 16 + lm) * Kd + kd + lg * 8;
      short8 b0 = *(const short8*)(Br);
      short8 b1 = *(const short8*)(Br + 32);
      acc[nf] = __builtin_amdgcn_mfma_f32_16x16x32_bf16(a0, b0, acc[nf], 0, 0, 0);
      acc[nf] = __builtin_amdgcn_mfma_f32_16x16x32_bf16(a1, b1, acc[nf], 0, 0, 0);
    }
  }

  if (MODE == 0) {
#pragma unroll
    for (int nf = 0; nf < 4; ++nf)
#pragma unroll
      for (int r = 0; r < 4; ++r)
        Cf[(size_t)(m0 + lg * 4 + r) * N + (n0 + nf * 16 + lm)] = acc[nf][r];
  } else {
    const float BL2E = 0.125f * 1.44269504088896340736f;
#pragma unroll
    for (int nf = 0; nf < 4; ++nf) {
      int n = n0 + nf * 16 + lm;
      int h = n >> 6, z = n & 63;
#pragma unroll
      for (int r = 0; r < 4; ++r) {
        int k = m0 + lg * 4 + r;
        Ck[((size_t)h * NCTX + k) * HD + z] = f2b(acc[nf][r] * BL2E);
        Ckt[((size_t)h * HD + z) * NCTX + k] = f2b(acc[nf][r]);
      }
    }
  }
}

// ---------------- 5-step energy attention, 8-wave / 128-k tiles ----------------
// 512 blocks = 16 heads x 32 q-tiles of 64 rows; 512 threads = 8 waves
// (kq 0-3 x qh 0-1). Staged tile: K 128x64 + Kt 64x128, double-buffered (64KB).
// Counted-vmcnt prefetch across raw s_barrier. Persistent q-state: f32 in
// REGISTERS (kq==0 waves; safe at VGPR cap 128 from min-waves=2 -- cap 64 was
// the rounds-5..11 spill). Transient bf16 q redistribution buffer lives in
// tile DEAD SPACE at bytes [48K,56K) (round-6 scheme). Total LDS = exactly
// 64KB -> 2 blocks/CU (65.5KB proven OK; 72KB/80KB gave 1 block).
__global__ __launch_bounds__(512, 2) void attn5(
    const u16* __restrict__ Kbf,   // [NH][NCTX][HD], pre-scaled by beta*log2e
    const u16* __restrict__ Ktb,   // [NH][HD][NCTX]
    const float* __restrict__ Qf,  // [NTGT][DMODEL]
    u16* __restrict__ Qob) {       // [NTGT][DMODEL] bf16
  __shared__ __align__(16) uint8_t smem[65536];
  u16*   sTu  = (u16*)smem;                  // [0, 64K): 2x32KB tile buffers
  u16*   qs16 = (u16*)(smem + 49152);        // [48K, 56K): transient bf16 q (merge phase only)
  float* lb   = (float*)(smem + 57344);      // merge-phase only (buf1 dead space)
  float* lf   = (float*)(smem + 58368);

  const int bid = blockIdx.x;
  const int h  = ((bid & 7) << 1) | ((bid >> 3) & 1);
  const int qt = bid >> 4;
  const int w = threadIdx.x >> 6, l = threadIdx.x & 63;
  const int ln = l & 31, hi = l >> 5;
  const int qh = w & 1, kq = w >> 1;
  const int q0w = qt * 64 + qh * 32;

  const u16* Kh  = Kbf + (size_t)h * NCTX * HD;
  const u16* Kth = Ktb + (size_t)h * HD * NCTX;

  auto STAGE = [&](int b, int t) {
    // K part: rows w*16..+16 of 128, 128B rows, S_K(r) = (r&7)^((r>>3)&7)
#pragma unroll
    for (int i = 0; i < 2; ++i) {
      const u16* src = Kh + (size_t)(t * 128 + w * 16 + i * 8 + (l >> 3)) * HD
                          + (((l & 7) ^ (l >> 3) ^ ((w * 2 + i) & 7)) << 3);
      __builtin_amdgcn_global_load_lds((g_u32*)src,
          (lds_u32*)(sTu + b * 16384 + (w * 16 + i * 8) * 64), 16, 0, 0);
    }
    // Kt part: z-rows w*8..+8 of 64, 256B rows, S_t(z) = z&15
#pragma unroll
    for (int i = 0; i < 2; ++i) {
      const u16* src = Kth + (size_t)(w * 8 + i * 4 + (l >> 4)) * NCTX + t * 128
                           + (((l & 15) ^ ((w * 8 + i * 4 + (l >> 4)) & 15)) << 3);
      __builtin_amdgcn_global_load_lds((g_u32*)src,
          (lds_u32*)(sTu + b * 16384 + 8192 + (w * 8 + i * 4) * 128), 16, 0, 0);
    }
  };

  // ---- Q B-frags: lane q=ln, z = zc*16 + 8*hi + e ----
  short8 qfrag[4];
  {
    const float* qp = Qf + (size_t)(q0w + ln) * DMODEL + h * HD + hi * 8;
#pragma unroll
    for (int zc = 0; zc < 4; ++zc) {
      float4 f0 = *(const float4*)(qp + zc * 16);
      float4 f1 = *(const float4*)(qp + zc * 16 + 4);
      union { short8 s; uint32_t u[4]; } t;
      t.u[0] = pk2(f0.x, f0.y); t.u[1] = pk2(f0.z, f0.w);
      t.u[2] = pk2(f1.x, f1.y); t.u[3] = pk2(f1.z, f1.w);
      qfrag[zc] = t.s;
    }
  }
  // ---- persistent q state: f32 registers, C-layout (kq==0 waves) ----
  float qreg[2][16];
  if (kq == 0) {
#pragma unroll
    for (int zb = 0; zb < 2; ++zb)
#pragma unroll
      for (int rr = 0; rr < 16; ++rr) {
        const int qq = (rr & 3) + 8 * (rr >> 2) + 4 * hi;
        qreg[zb][rr] = Qf[(size_t)(q0w + qq) * DMODEL + h * HD + zb * 32 + ln];
      }
  }

  STAGE(0, 0);

  for (int step = 0; step < 5; ++step) {
    f32x16 acc0 = {}, acc1 = {};
    float lrow = 0.f;

#pragma unroll 2
    for (int t = 0; t < 32; ++t) {
      const int buf = t & 1;
      asm volatile("s_waitcnt vmcnt(0)" ::: "memory");  // own tile-t loads done
      __builtin_amdgcn_s_barrier();                     // everyone's tile-t done
      if (t < 31) STAGE(buf ^ 1, t + 1);                // prefetch stays in flight
      const u16* tb = sTu + buf * 16384;

      // ---- St = K_strip * Q^T (k rows kq*32+ln, q cols = lanes) ----
      f32x16 st = {};
#pragma unroll
      for (int zc = 0; zc < 4; ++zc) {
        const int b7 = (zc * 2 + hi) ^ (ln & 7) ^ ((kq * 4 + (ln >> 3)) & 7);
        short8 kf = *(const short8*)(tb + (kq * 32 + ln) * 64 + (b7 << 3));
        st = __builtin_amdgcn_mfma_f32_32x32x16_bf16(kf, qfrag[zc], st, 0, 0, 0);
      }
      // ---- P = exp2(St); pack via cvt_pk + permlane32_swap; PV ----
      const u16* kt = tb + 8192;
#pragma unroll
      for (int kc = 0; kc < 2; ++kc) {
        float p0 = exp2f(st[8 * kc + 0]), p1 = exp2f(st[8 * kc + 1]);
        float p2 = exp2f(st[8 * kc + 2]), p3 = exp2f(st[8 * kc + 3]);
        float p4 = exp2f(st[8 * kc + 4]), p5 = exp2f(st[8 * kc + 5]);
        float p6 = exp2f(st[8 * kc + 6]), p7 = exp2f(st[8 * kc + 7]);
        lrow += ((p0 + p1) + (p2 + p3)) + ((p4 + p5) + (p6 + p7));
        uint32_t a0 = pk2(p0, p1), a1 = pk2(p2, p3);
        uint32_t b0 = pk2(p4, p5), b1 = pk2(p6, p7);
        asm("v_permlane32_swap_b32 %0, %1" : "+v"(a0), "+v"(b0));
        asm("v_permlane32_swap_b32 %0, %1" : "+v"(a1), "+v"(b1));
        union { short8 s; uint32_t u[4]; } pa;
        pa.u[0] = a0; pa.u[1] = a1; pa.u[2] = b0; pa.u[3] = b1;
        const int b16 = (kq * 4 + kc * 2 + hi) ^ (ln & 15);
        short8 v0 = *(const short8*)(kt + ln * 128 + (b16 << 3));
        short8 v1 = *(const short8*)(kt + (32 + ln) * 128 + (b16 << 3));
        acc0 = __builtin_amdgcn_mfma_f32_32x32x16_bf16(pa.s, v0, acc0, 0, 0, 0);
        acc1 = __builtin_amdgcn_mfma_f32_32x32x16_bf16(pa.s, v1, acc1, 0, 0, 0);
      }
    }

    __syncthreads();                       // all compute done; sTu free
    lrow += __shfl_xor(lrow, 32);

    float* md = (float*)sTu;               // bytes [0, 48K): 6 partial dumps
    if (kq != 0) {
      float* my = md + ((kq - 1) * 2 + qh) * 2048;
#pragma unroll
      for (int rr = 0; rr < 16; ++rr) {
        my[rr * 64 + l] = acc0[rr];
        my[(rr + 16) * 64 + l] = acc1[rr];
      }
      if (hi == 0) lb[(kq * 2 + qh) * 32 + ln] = lrow;
    }
    __syncthreads();
    if (kq == 0) {
      float lt = lrow + lb[(2 + qh) * 32 + ln] + lb[(4 + qh) * 32 + ln]
               + lb[(6 + qh) * 32 + ln];
      if (hi == 0) lf[qh * 32 + ln] = lt;
#pragma unroll
      for (int rr = 0; rr < 16; ++rr) {
        acc0[rr] += md[qh * 2048 + rr * 64 + l] + md[(2 + qh) * 2048 + rr * 64 + l]
                  + md[(4 + qh) * 2048 + rr * 64 + l];
        acc1[rr] += md[qh * 2048 + (rr + 16) * 64 + l] + md[(2 + qh) * 2048 + (rr + 16) * 64 + l]
                  + md[(4 + qh) * 2048 + (rr + 16) * 64 + l];
      }
      u16* qsm = qs16 + qh * 2048;
#pragma unroll
      for (int rr = 0; rr < 16; ++rr) {
        const int qq = (rr & 3) + 8 * (rr >> 2) + 4 * hi;
        const float sc = 0.1f / lf[qh * 32 + qq];
        qreg[0][rr] += acc0[rr] * sc;
        qreg[1][rr] += acc1[rr] * sc;
        if (step < 4) {
          qsm[qq * 64 + ((((ln >> 3)) ^ (qq & 7)) << 3) + (ln & 7)] = f2b(qreg[0][rr]);
          qsm[qq * 64 + ((((ln >> 3) + 4) ^ (qq & 7)) << 3) + (ln & 7)] = f2b(qreg[1][rr]);
        } else {
          const size_t base = (size_t)(q0w + qq) * DMODEL + h * HD;
          Qob[base + ln] = f2b(qreg[0][rr]);
          Qob[base + 32 + ln] = f2b(qreg[1][rr]);
        }
      }
    }
    if (step < 4) {
      __syncthreads();                     // qs16 visible to all waves
      const u16* qsr = qs16 + qh * 2048;
#pragma unroll
      for (int zc = 0; zc < 4; ++zc)
        qfrag[zc] = *(const short8*)(qsr + ln * 64 + (((zc * 2 + hi) ^ (ln & 7)) << 3));
      STAGE(0, 0);                         // writes bytes [0, 32K), no overlap
    }
  }
}

extern "C" void kernel_launch(void* const* d_in, const int* in_sizes, int n_in,
                              void* d_out, int out_size, void* d_ws, size_t ws_size,
                              hipStream_t stream) {
  const float* ctx = (const float*)d_in[0];
  const float* tgt = (const float*)d_in[1];
  const float* Wq  = (const float*)d_in[2];
  const float* Wk  = (const float*)d_in[3];
  const float* Wo  = (const float*)d_in[4];

  uint8_t* wp = (uint8_t*)d_ws;
  u16* ctxb = (u16*)wp; wp += (size_t)NCTX * DMODEL * 2;
  u16* tgtb = (u16*)wp; wp += (size_t)NTGT * DMODEL * 2;
  u16* wqb  = (u16*)wp; wp += (size_t)DMODEL * DMODEL * 2;
  u16* wkb  = (u16*)wp; wp += (size_t)DMODEL * DMODEL * 2;
  u16* wob  = (u16*)wp; wp += (size_t)DMODEL * DMODEL * 2;
  u16* Kbf  = (u16*)wp; wp += (size_t)NH * NCTX * HD * 2;
  u16* Ktb  = (u16*)wp; wp += (size_t)NH * HD * NCTX * 2;
  float* Qf = (float*)wp; wp += (size_t)NTGT * DMODEL * 4;
  u16* Qob  = (u16*)wp; wp += (size_t)NTGT * DMODEL * 2;

  auto cvt = [&](const float* in, u16* out, size_t n) {
    int n4 = (int)(n / 4);
    hipLaunchKernelGGL(cvt_bf16, dim3((n4 + 255) / 256), dim3(256), 0, stream, in, out, n4);
  };
  cvt(ctx, ctxb, (size_t)NCTX * DMODEL);
  cvt(tgt, tgtb, (size_t)NTGT * DMODEL);
  cvt(Wq, wqb, (size_t)DMODEL * DMODEL);
  cvt(Wk, wkb, (size_t)DMODEL * DMODEL);
  cvt(Wo, wob, (size_t)DMODEL * DMODEL);

  hipLaunchKernelGGL(gemm_bt<1>, dim3((NCTX / 64) * (DMODEL / 64)), dim3(256), 0, stream,
                     ctxb, wkb, (float*)nullptr, Kbf, Ktb, NCTX, DMODEL, DMODEL);
  hipLaunchKernelGGL(gemm_bt<0>, dim3((NTGT / 64) * (DMODEL / 64)), dim3(256), 0, stream,
                     tgtb, wqb, Qf, (u16*)nullptr, (u16*)nullptr, NTGT, DMODEL, DMODEL);
  hipLaunchKernelGGL(attn5, dim3(512), dim3(512), 0, stream, Kbf, Ktb, Qf, Qob);
  hipLaunchKernelGGL(gemm_bt<0>, dim3((NTGT / 64) * (DMODEL / 64)), dim3(256), 0, stream,
                     Qob, wob, (float*)d_out, (u16*)nullptr, (u16*)nullptr, NTGT, DMODEL, DMODEL);
}

// Round 15
// 448.607 us; speedup vs baseline: 1.0858x; 1.0858x over previous
//
#include <hip/hip_runtime.h>
#include <stdint.h>

typedef unsigned short u16;
typedef __attribute__((ext_vector_type(8))) short short8;
typedef __attribute__((ext_vector_type(4))) float f32x4;
typedef __attribute__((ext_vector_type(16))) float f32x16;

#define NCTX 4096
#define NTGT 2048
#define DMODEL 1024
#define NH 16
#define HD 64

typedef const __attribute__((address_space(1))) uint32_t g_u32;
typedef __attribute__((address_space(3))) uint32_t lds_u32;

__device__ inline u16 f2b(float f) {
  unsigned r;
  asm("v_cvt_pk_bf16_f32 %0, %1, %1" : "=v"(r) : "v"(f));
  return (u16)r;
}
__device__ inline uint32_t pk2(float lo, float hi_) {
  uint32_t r;
  asm("v_cvt_pk_bf16_f32 %0, %1, %2" : "=v"(r) : "v"(lo), "v"(hi_));
  return r;
}

// ---------------- f32 -> bf16 conversion ----------------
__global__ void cvt_bf16(const float* __restrict__ in, u16* __restrict__ out, int n4) {
  int i = blockIdx.x * blockDim.x + threadIdx.x;
  if (i >= n4) return;
  const float4 v = ((const float4*)in)[i];
  ((uint2*)out)[i] = make_uint2(pk2(v.x, v.y), pk2(v.z, v.w));
}

// ---------------- generic C = A * B^T  (bf16 in, f32 accum) ----------------
// MODE 1: K-writer; Ck is pre-scaled by beta*log2e (used only for scores).
template<int MODE>
__global__ __launch_bounds__(256) void gemm_bt(
    const u16* __restrict__ A, const u16* __restrict__ B,
    float* __restrict__ Cf, u16* __restrict__ Ck, u16* __restrict__ Ckt,
    int M, int N, int Kd) {
  const int bm = blockIdx.x % (M >> 6);
  const int bn = blockIdx.x / (M >> 6);
  const int w = threadIdx.x >> 6, l = threadIdx.x & 63;
  const int lg = l >> 4, lm = l & 15;
  const int m0 = (bm << 6) + (w << 4);
  const int n0 = bn << 6;

  const u16* Ar = A + (size_t)(m0 + lm) * Kd;
  f32x4 acc[4] = {};

  for (int kd = 0; kd < Kd; kd += 64) {
    short8 a0 = *(const short8*)(Ar + kd + lg * 8);
    short8 a1 = *(const short8*)(Ar + kd + 32 + lg * 8);
#pragma unroll
    for (int nf = 0; nf < 4; ++nf) {
      const u16* Br = B + (size_t)(n0 + nf * 16 + lm) * Kd + kd + lg * 8;
      short8 b0 = *(const short8*)(Br);
      short8 b1 = *(const short8*)(Br + 32);
      acc[nf] = __builtin_amdgcn_mfma_f32_16x16x32_bf16(a0, b0, acc[nf], 0, 0, 0);
      acc[nf] = __builtin_amdgcn_mfma_f32_16x16x32_bf16(a1, b1, acc[nf], 0, 0, 0);
    }
  }

  if (MODE == 0) {
#pragma unroll
    for (int nf = 0; nf < 4; ++nf)
#pragma unroll
      for (int r = 0; r < 4; ++r)
        Cf[(size_t)(m0 + lg * 4 + r) * N + (n0 + nf * 16 + lm)] = acc[nf][r];
  } else {
    const float BL2E = 0.125f * 1.44269504088896340736f;
#pragma unroll
    for (int nf = 0; nf < 4; ++nf) {
      int n = n0 + nf * 16 + lm;
      int h = n >> 6, z = n & 63;
#pragma unroll
      for (int r = 0; r < 4; ++r) {
        int k = m0 + lg * 4 + r;
        Ck[((size_t)h * NCTX + k) * HD + z] = f2b(acc[nf][r] * BL2E);
        Ckt[((size_t)h * HD + z) * NCTX + k] = f2b(acc[nf][r]);
      }
    }
  }
}

// ---------------- 5-step energy attention, 8-wave / 128-k tiles ----------------
// 512 blocks = 16 heads x 32 q-tiles of 64 rows; 512 threads = 8 waves
// (kq 0-3 x qh 0-1). Staged tile: K 128x64 + Kt 64x128, double-buffered (64KB).
// Counted-vmcnt prefetch across raw s_barrier. DISTRIBUTED q-state: wave
// (kq,qh) owns rows [8kq,8kq+8) of its qh group -> only 8 f32/thread, so the
// total (arch+acc) VGPR live set fits the 128/thread budget that
// __launch_bounds__(512,4) enforces -> 4 waves/SIMD, 2 blocks/CU, no spill.
// Symmetric merge: all 8 waves dump partial O (64KB = all of sTu), then each
// wave merges its own rows. qs16 overlays dump region 6 (barrier-protected).
__global__ __launch_bounds__(512, 4) void attn5(
    const u16* __restrict__ Kbf,   // [NH][NCTX][HD], pre-scaled by beta*log2e
    const u16* __restrict__ Ktb,   // [NH][HD][NCTX]
    const float* __restrict__ Qf,  // [NTGT][DMODEL]
    u16* __restrict__ Qob) {       // [NTGT][DMODEL] bf16
  __shared__ __align__(16) u16 sTu[32768];   // 64KB: 2x32KB tile buffers
  __shared__ float lb[8][32];                // 1KB: per-wave row-sum partials

  const int bid = blockIdx.x;
  const int h  = ((bid & 7) << 1) | ((bid >> 3) & 1);
  const int qt = bid >> 4;
  const int w = threadIdx.x >> 6, l = threadIdx.x & 63;
  const int ln = l & 31, hi = l >> 5;
  const int qh = w & 1, kq = w >> 1;
  const int q0w = qt * 64 + qh * 32;

  const u16* Kh  = Kbf + (size_t)h * NCTX * HD;
  const u16* Kth = Ktb + (size_t)h * HD * NCTX;

  auto STAGE = [&](int b, int t) {
    // K part: rows w*16..+16 of 128, 128B rows, S_K(r) = (r&7)^((r>>3)&7)
#pragma unroll
    for (int i = 0; i < 2; ++i) {
      const u16* src = Kh + (size_t)(t * 128 + w * 16 + i * 8 + (l >> 3)) * HD
                          + (((l & 7) ^ (l >> 3) ^ ((w * 2 + i) & 7)) << 3);
      __builtin_amdgcn_global_load_lds((g_u32*)src,
          (lds_u32*)(sTu + b * 16384 + (w * 16 + i * 8) * 64), 16, 0, 0);
    }
    // Kt part: z-rows w*8..+8 of 64, 256B rows, S_t(z) = z&15
#pragma unroll
    for (int i = 0; i < 2; ++i) {
      const u16* src = Kth + (size_t)(w * 8 + i * 4 + (l >> 4)) * NCTX + t * 128
                           + (((l & 15) ^ ((w * 8 + i * 4 + (l >> 4)) & 15)) << 3);
      __builtin_amdgcn_global_load_lds((g_u32*)src,
          (lds_u32*)(sTu + b * 16384 + 8192 + (w * 8 + i * 4) * 128), 16, 0, 0);
    }
  };

  // ---- Q B-frags: lane q=ln, z = zc*16 + 8*hi + e ----
  short8 qfrag[4];
  {
    const float* qp = Qf + (size_t)(q0w + ln) * DMODEL + h * HD + hi * 8;
#pragma unroll
    for (int zc = 0; zc < 4; ++zc) {
      float4 f0 = *(const float4*)(qp + zc * 16);
      float4 f1 = *(const float4*)(qp + zc * 16 + 4);
      union { short8 s; uint32_t u[4]; } t;
      t.u[0] = pk2(f0.x, f0.y); t.u[1] = pk2(f0.z, f0.w);
      t.u[2] = pk2(f1.x, f1.y); t.u[3] = pk2(f1.z, f1.w);
      qfrag[zc] = t.s;
    }
  }
  // ---- distributed q-state: rows qq = i + 8*kq + 4*hi, cols ln / 32+ln ----
  float qst0[4], qst1[4];
#pragma unroll
  for (int i = 0; i < 4; ++i) {
    const int qq = i + 8 * kq + 4 * hi;
    const float* qp = Qf + (size_t)(q0w + qq) * DMODEL + h * HD;
    qst0[i] = qp[ln];
    qst1[i] = qp[32 + ln];
  }

  STAGE(0, 0);

  for (int step = 0; step < 5; ++step) {
    f32x16 acc0 = {}, acc1 = {};
    float lrow = 0.f;

#pragma unroll 2
    for (int t = 0; t < 32; ++t) {
      const int buf = t & 1;
      asm volatile("s_waitcnt vmcnt(0)" ::: "memory");  // own tile-t loads done
      __builtin_amdgcn_s_barrier();                     // everyone's tile-t done
      if (t < 31) STAGE(buf ^ 1, t + 1);                // prefetch stays in flight
      const u16* tb = sTu + buf * 16384;

      // ---- St = K_strip * Q^T (k rows kq*32+ln, q cols = lanes) ----
      f32x16 st = {};
#pragma unroll
      for (int zc = 0; zc < 4; ++zc) {
        const int b7 = (zc * 2 + hi) ^ (ln & 7) ^ ((kq * 4 + (ln >> 3)) & 7);
        short8 kf = *(const short8*)(tb + (kq * 32 + ln) * 64 + (b7 << 3));
        st = __builtin_amdgcn_mfma_f32_32x32x16_bf16(kf, qfrag[zc], st, 0, 0, 0);
      }
      // ---- P = exp2(St); pack via cvt_pk + permlane32_swap; PV ----
      const u16* kt = tb + 8192;
#pragma unroll
      for (int kc = 0; kc < 2; ++kc) {
        float p0 = exp2f(st[8 * kc + 0]), p1 = exp2f(st[8 * kc + 1]);
        float p2 = exp2f(st[8 * kc + 2]), p3 = exp2f(st[8 * kc + 3]);
        float p4 = exp2f(st[8 * kc + 4]), p5 = exp2f(st[8 * kc + 5]);
        float p6 = exp2f(st[8 * kc + 6]), p7 = exp2f(st[8 * kc + 7]);
        lrow += ((p0 + p1) + (p2 + p3)) + ((p4 + p5) + (p6 + p7));
        uint32_t a0 = pk2(p0, p1), a1 = pk2(p2, p3);
        uint32_t b0 = pk2(p4, p5), b1 = pk2(p6, p7);
        asm("v_permlane32_swap_b32 %0, %1" : "+v"(a0), "+v"(b0));
        asm("v_permlane32_swap_b32 %0, %1" : "+v"(a1), "+v"(b1));
        union { short8 s; uint32_t u[4]; } pa;
        pa.u[0] = a0; pa.u[1] = a1; pa.u[2] = b0; pa.u[3] = b1;
        const int b16 = (kq * 4 + kc * 2 + hi) ^ (ln & 15);
        short8 v0 = *(const short8*)(kt + ln * 128 + (b16 << 3));
        short8 v1 = *(const short8*)(kt + (32 + ln) * 128 + (b16 << 3));
        acc0 = __builtin_amdgcn_mfma_f32_32x32x16_bf16(pa.s, v0, acc0, 0, 0, 0);
        acc1 = __builtin_amdgcn_mfma_f32_32x32x16_bf16(pa.s, v1, acc1, 0, 0, 0);
      }
    }

    __syncthreads();                       // all compute done; sTu free
    lrow += __shfl_xor(lrow, 32);

    // ---- symmetric dump: all 8 waves write their partials ----
    float* md = (float*)sTu;               // 8 regions x 8KB = 64KB
    float* my = md + (kq * 2 + qh) * 2048;
#pragma unroll
    for (int rr = 0; rr < 16; ++rr) {
      my[rr * 64 + l] = acc0[rr];
      my[(rr + 16) * 64 + l] = acc1[rr];
    }
    if (hi == 0) lb[kq * 2 + qh][ln] = lrow;
    __syncthreads();

    // ---- distributed merge: wave (kq,qh) handles rr in [4kq, 4kq+4) ----
#pragma unroll
    for (int i = 0; i < 4; ++i) {
      const int rr = 4 * kq + i;
      const int qq = i + 8 * kq + 4 * hi;
      const float o0 = md[qh * 2048 + rr * 64 + l] + md[(2 + qh) * 2048 + rr * 64 + l]
                     + md[(4 + qh) * 2048 + rr * 64 + l] + md[(6 + qh) * 2048 + rr * 64 + l];
      const float o1 = md[qh * 2048 + (rr + 16) * 64 + l] + md[(2 + qh) * 2048 + (rr + 16) * 64 + l]
                     + md[(4 + qh) * 2048 + (rr + 16) * 64 + l] + md[(6 + qh) * 2048 + (rr + 16) * 64 + l];
      const float lt = lb[qh][qq] + lb[2 + qh][qq] + lb[4 + qh][qq] + lb[6 + qh][qq];
      const float sc = 0.1f / lt;
      qst0[i] += o0 * sc;
      qst1[i] += o1 * sc;
    }

    if (step < 4) {
      __syncthreads();                     // all dump reads done; region 6 free
      u16* qsm = sTu + 24576 + qh * 2048;  // bytes [48K,56K), overlays region 6
#pragma unroll
      for (int i = 0; i < 4; ++i) {
        const int qq = i + 8 * kq + 4 * hi;
        qsm[qq * 64 + ((((ln >> 3)) ^ (qq & 7)) << 3) + (ln & 7)] = f2b(qst0[i]);
        qsm[qq * 64 + ((((ln >> 3) + 4) ^ (qq & 7)) << 3) + (ln & 7)] = f2b(qst1[i]);
      }
      __syncthreads();                     // qs16 visible to all waves
      const u16* qsr = sTu + 24576 + qh * 2048;
#pragma unroll
      for (int zc = 0; zc < 4; ++zc)
        qfrag[zc] = *(const short8*)(qsr + ln * 64 + (((zc * 2 + hi) ^ (ln & 7)) << 3));
      STAGE(0, 0);                         // writes bytes [0, 32K), no overlap
    } else {
#pragma unroll
      for (int i = 0; i < 4; ++i) {
        const int qq = i + 8 * kq + 4 * hi;
        const size_t base = (size_t)(q0w + qq) * DMODEL + h * HD;
        Qob[base + ln] = f2b(qst0[i]);
        Qob[base + 32 + ln] = f2b(qst1[i]);
      }
    }
  }
}

extern "C" void kernel_launch(void* const* d_in, const int* in_sizes, int n_in,
                              void* d_out, int out_size, void* d_ws, size_t ws_size,
                              hipStream_t stream) {
  const float* ctx = (const float*)d_in[0];
  const float* tgt = (const float*)d_in[1];
  const float* Wq  = (const float*)d_in[2];
  const float* Wk  = (const float*)d_in[3];
  const float* Wo  = (const float*)d_in[4];

  uint8_t* wp = (uint8_t*)d_ws;
  u16* ctxb = (u16*)wp; wp += (size_t)NCTX * DMODEL * 2;
  u16* tgtb = (u16*)wp; wp += (size_t)NTGT * DMODEL * 2;
  u16* wqb  = (u16*)wp; wp += (size_t)DMODEL * DMODEL * 2;
  u16* wkb  = (u16*)wp; wp += (size_t)DMODEL * DMODEL * 2;
  u16* wob  = (u16*)wp; wp += (size_t)DMODEL * DMODEL * 2;
  u16* Kbf  = (u16*)wp; wp += (size_t)NH * NCTX * HD * 2;
  u16* Ktb  = (u16*)wp; wp += (size_t)NH * HD * NCTX * 2;
  float* Qf = (float*)wp; wp += (size_t)NTGT * DMODEL * 4;
  u16* Qob  = (u16*)wp; wp += (size_t)NTGT * DMODEL * 2;

  auto cvt = [&](const float* in, u16* out, size_t n) {
    int n4 = (int)(n / 4);
    hipLaunchKernelGGL(cvt_bf16, dim3((n4 + 255) / 256), dim3(256), 0, stream, in, out, n4);
  };
  cvt(ctx, ctxb, (size_t)NCTX * DMODEL);
  cvt(tgt, tgtb, (size_t)NTGT * DMODEL);
  cvt(Wq, wqb, (size_t)DMODEL * DMODEL);
  cvt(Wk, wkb, (size_t)DMODEL * DMODEL);
  cvt(Wo, wob, (size_t)DMODEL * DMODEL);

  hipLaunchKernelGGL(gemm_bt<1>, dim3((NCTX / 64) * (DMODEL / 64)), dim3(256), 0, stream,
                     ctxb, wkb, (float*)nullptr, Kbf, Ktb, NCTX, DMODEL, DMODEL);
  hipLaunchKernelGGL(gemm_bt<0>, dim3((NTGT / 64) * (DMODEL / 64)), dim3(256), 0, stream,
                     tgtb, wqb, Qf, (u16*)nullptr, (u16*)nullptr, NTGT, DMODEL, DMODEL);
  hipLaunchKernelGGL(attn5, dim3(512), dim3(512), 0, stream, Kbf, Ktb, Qf, Qob);
  hipLaunchKernelGGL(gemm_bt<0>, dim3((NTGT / 64) * (DMODEL / 64)), dim3(256), 0, stream,
                     Qob, wob, (float*)d_out, (u16*)nullptr, (u16*)nullptr, NTGT, DMODEL, DMODEL);
}